// Round 3
// baseline (253.405 us; speedup 1.0000x reference)
//
#include <hip/hip_runtime.h>
#include <hip/hip_bf16.h>
#include <math.h>

// out[b,s,d] = x[b,s,d] + enc(s,d)
// enc(s,d) = even(d) ? sin(s * 10000^(-d/D)) : cos(s * 10000^(-d/D))
// x: fp32 [B=8, S=4096, D=1024]. Memory-bound streaming add.
//
// R1 lesson: runtime `break` inside the b-loop serialized the 8 load/store
// round-trips (1 outstanding load/thread -> latency-bound, 2.5 TB/s).
// R2 lesson: __builtin_nontemporal_store needs a clang ext_vector_type, not
// HIP's float4 class. Use vf4 = float ext_vector_type(4).
// Plan: hardcode B=8, issue all 8 float4 loads into registers (8-deep MLP),
// then add+store nontemporally (output never re-read; keep L3 for x).

#define S_LEN 4096
#define D_LEN 1024

typedef float vf4 __attribute__((ext_vector_type(4)));

__global__ __launch_bounds__(256) void pe_add_kernel8(
    const float* __restrict__ x, float* __restrict__ out) {
    const int s   = blockIdx.x;           // 0..4095
    const int tid = threadIdx.x;          // 0..255
    const int d0  = tid << 2;             // 4 consecutive dims

    const size_t base    = (size_t)s * D_LEN + (size_t)d0;
    const size_t bstride = (size_t)S_LEN * D_LEN;

    // Issue all 8 batch loads back-to-back (independent, 8 in flight).
    vf4 v[8];
    #pragma unroll
    for (int b = 0; b < 8; ++b) {
        v[b] = *(const vf4*)(x + base + (size_t)b * bstride);
    }

    // enc for this thread's 4 dims (batch-invariant, computed once while
    // the loads are in flight).
    const float sf = (float)s;
    const float c  = -9.210340371976184f / (float)D_LEN;  // -ln(10000)/1024
    vf4 e;
    e.x = sinf(sf * expf((float)(d0 + 0) * c));  // even dim -> sin
    e.y = cosf(sf * expf((float)(d0 + 1) * c));  // odd  dim -> cos
    e.z = sinf(sf * expf((float)(d0 + 2) * c));
    e.w = cosf(sf * expf((float)(d0 + 3) * c));

    #pragma unroll
    for (int b = 0; b < 8; ++b) {
        vf4 r = v[b] + e;
        __builtin_nontemporal_store(r, (vf4*)(out + base + (size_t)b * bstride));
    }
}

// Fallback for unexpected B (keeps correctness general).
__global__ __launch_bounds__(256) void pe_add_kernel_gen(
    const float* __restrict__ x, float* __restrict__ out, int B) {
    const int s   = blockIdx.x;
    const int tid = threadIdx.x;
    const int d0  = tid << 2;

    const float sf = (float)s;
    const float c  = -9.210340371976184f / (float)D_LEN;
    vf4 e;
    e.x = sinf(sf * expf((float)(d0 + 0) * c));
    e.y = cosf(sf * expf((float)(d0 + 1) * c));
    e.z = sinf(sf * expf((float)(d0 + 2) * c));
    e.w = cosf(sf * expf((float)(d0 + 3) * c));

    const size_t base    = (size_t)s * D_LEN + (size_t)d0;
    const size_t bstride = (size_t)S_LEN * D_LEN;
    for (int b = 0; b < B; ++b) {
        vf4 r = *(const vf4*)(x + base + (size_t)b * bstride) + e;
        *(vf4*)(out + base + (size_t)b * bstride) = r;
    }
}

extern "C" void kernel_launch(void* const* d_in, const int* in_sizes, int n_in,
                              void* d_out, int out_size, void* d_ws, size_t ws_size,
                              hipStream_t stream) {
    const float* x = (const float*)d_in[0];
    float* out = (float*)d_out;
    const int B = in_sizes[0] / (S_LEN * D_LEN);  // = 8

    dim3 grid(S_LEN);        // one block per sequence position
    dim3 block(D_LEN / 4);   // 256 threads, one float4 each
    if (B == 8) {
        pe_add_kernel8<<<grid, block, 0, stream>>>(x, out);
    } else {
        pe_add_kernel_gen<<<grid, block, 0, stream>>>(x, out, B);
    }
}